// Round 12
// baseline (241.940 us; speedup 1.0000x reference)
//
#include <hip/hip_runtime.h>
#include <hip/hip_fp16.h>
#include <math.h>

#define CAP 64          // max incidences per node (mean deg = 8)
#define D1 128
#define D2 16
#define C_OUT 40
#define K_EDGE 32
#define CLAMP_LO 1e-7f
#define CLAMP_HI 10.0f
#define SQRT_INV31 0.1796053020267749f   // sqrt(1/31)

typedef unsigned short ushort_t;
typedef _Float16 h2v __attribute__((ext_vector_type(2)));   // packed fp16 pair

// Pure-streaming setup: clip+square -> Hp (fp16), W1 transpose, zero rows of
// S/S2, deg zeroing, and lst zeroing (needed: build now uses atomicOr).
__global__ __launch_bounds__(256) void k_setup(const float* __restrict__ x,
                                               __half2* __restrict__ Hp,
                                               const float* __restrict__ W1,
                                               float* __restrict__ W1t,
                                               __half2* __restrict__ S,
                                               float* __restrict__ S2,
                                               int* __restrict__ deg,
                                               uint2* __restrict__ lstz,
                                               int n4, int N, int E) {
    int i = blockIdx.x * 256 + threadIdx.x;
    if (i < n4) {                                  // clip + square, 4 floats
        float4 v = ((const float4*)x)[i];
        v.x = fminf(fmaxf(v.x, CLAMP_LO), CLAMP_HI);
        v.y = fminf(fmaxf(v.y, CLAMP_LO), CLAMP_HI);
        v.z = fminf(fmaxf(v.z, CLAMP_LO), CLAMP_HI);
        v.w = fminf(fmaxf(v.w, CLAMP_LO), CLAMP_HI);
        __half2 h0 = __floats2half2_rn(v.x * v.x, v.y * v.y);
        __half2 h1 = __floats2half2_rn(v.z * v.z, v.w * v.w);
        uint2 st;
        __builtin_memcpy(&st.x, &h0, 4);
        __builtin_memcpy(&st.y, &h1, 4);
        ((uint2*)Hp)[i] = st;                      // one 8B store
    }
    if (i < N * 16) lstz[i] = make_uint2(0u, 0u);  // zero lst (12.8 MB)
    if (i < N) deg[i] = 0;
    if (i < D1 * D2) W1t[(i & 15) * D1 + (i >> 4)] = W1[i];
    if (i < 64) S[(size_t)E * 64 + i] = __floats2half2_rn(0.0f, 0.0f);
    if (i < D2) S2[(size_t)E * D2 + i] = 0.0f;
}

// S[e,:] = sum of Hp[node,:] over the edge's 32 nodes + fused incidence
// build. COLUMN-QUARTER split: wave = 4 edges x one 64B row-quarter,
// quarter q = blockIdx%4 -> with XCD = blockIdx%8 each XCD touches only
// one quarter of every Hp row (per-XCD set 16 -> 6.3 MB ~ L2). Build via
// fire-and-forget atomicOr (no dirty-line RMW writebacks; lst zero-init'd),
// rotated to wave w==q so all quarters share build work. Per-edge j-loop
// cost unchanged (1 load + 2 cvt + 2 add); S sum order bitwise-identical.
__global__ __launch_bounds__(256) void k_edge_sum(const __half2* __restrict__ Hp,
                                                  const int* __restrict__ idx,
                                                  __half2* __restrict__ S,
                                                  int* __restrict__ deg,
                                                  unsigned int* __restrict__ lstw,
                                                  int E) {
    int w = threadIdx.x >> 6;
    int lane = threadIdx.x & 63;
    int q = blockIdx.x & 3;                 // quarter (XCD b%8 -> quarter b%4)
    int g = blockIdx.x >> 2;
    int eA = g * 16 + w * 4;                // 4 edges per wave; E % 4 == 0
    if (eA >= E) return;
    int col = lane & 15;                    // half2 col within quarter
    int ed = lane >> 4;                     // edge select for the store
    int qoff = q * 16;                      // half2 offset of quarter in row

    int nid0 = idx[eA * K_EDGE + lane];     // ids of edges eA, eA+1
    int nid1 = idx[(eA + 2) * K_EDGE + lane];   // ids of edges eA+2, eA+3

    float a0 = 0.0f, a1 = 0.0f, b0 = 0.0f, b1 = 0.0f;
    float c0 = 0.0f, c1 = 0.0f, d0 = 0.0f, d1 = 0.0f;
#pragma unroll
    for (int j = 0; j < K_EDGE; j++) {
        int nA = __builtin_amdgcn_readlane(nid0, j);
        int nB = __builtin_amdgcn_readlane(nid0, 32 + j);
        int nC = __builtin_amdgcn_readlane(nid1, j);
        int nD = __builtin_amdgcn_readlane(nid1, 32 + j);
        __half2 hA = Hp[(size_t)nA * 64 + qoff + col];
        __half2 hB = Hp[(size_t)nB * 64 + qoff + col];
        __half2 hC = Hp[(size_t)nC * 64 + qoff + col];
        __half2 hD = Hp[(size_t)nD * 64 + qoff + col];
        a0 += __low2float(hA); a1 += __high2float(hA);
        b0 += __low2float(hB); b1 += __high2float(hB);
        c0 += __low2float(hC); c1 += __high2float(hC);
        d0 += __low2float(hD); d1 += __high2float(hD);
    }

    // incidence build, rotated: quarter-q block builds its wave w==q edges
    if (w == q) {
        int e0 = eA + (lane >> 5);
        int pos0 = atomicAdd(&deg[nid0], 1);
        if (pos0 < CAP)
            atomicOr(&lstw[nid0 * (CAP / 2) + (pos0 >> 1)],
                     (unsigned int)(ushort_t)e0 << (16 * (pos0 & 1)));
        int e1 = eA + 2 + (lane >> 5);
        int pos1 = atomicAdd(&deg[nid1], 1);
        if (pos1 < CAP)
            atomicOr(&lstw[nid1 * (CAP / 2) + (pos1 >> 1)],
                     (unsigned int)(ushort_t)e1 << (16 * (pos1 & 1)));
    }

    float s0 = (ed == 0) ? a0 : (ed == 1) ? b0 : (ed == 2) ? c0 : d0;
    float s1 = (ed == 0) ? a1 : (ed == 1) ? b1 : (ed == 2) ? c1 : d1;
    S[(size_t)(eA + ed) * 64 + qoff + col] = __floats2half2_rn(s0, s1);
}

// 4-slot fp16 partial: p = sum of sqrt_f16(max(s[t]-hp,0)), t in [base,base+4)
#define SQ4(p, s, base, hp)                                                   \
    {                                                                         \
        h2v d0_ = __builtin_elementwise_max((s)[(base) + 0] - (hp), zv);      \
        h2v d1_ = __builtin_elementwise_max((s)[(base) + 1] - (hp), zv);      \
        h2v d2_ = __builtin_elementwise_max((s)[(base) + 2] - (hp), zv);      \
        h2v d3_ = __builtin_elementwise_max((s)[(base) + 3] - (hp), zv);      \
        p = __builtin_elementwise_sqrt(d0_) + __builtin_elementwise_sqrt(d1_) \
          + __builtin_elementwise_sqrt(d2_) + __builtin_elementwise_sqrt(d3_);\
    }

// Fused layer-1 node kernel. FOUR nodes per wave; gathers for slots 0..11
// unconditional; compute gated per node-PAIR; fp16 sqrt + 4-slot partials.
__global__ __launch_bounds__(256) void k_node1(const __half2* __restrict__ Hp,
                                               const __half2* __restrict__ S,
                                               const int* __restrict__ deg,
                                               const ushort_t* __restrict__ lst,
                                               const float* __restrict__ W1t,
                                               const float* __restrict__ b1,
                                               float* __restrict__ Hp2, int N, int E) {
    int w = threadIdx.x >> 6;
    int lane = threadIdx.x & 63;
    int quad = blockIdx.x * 4 + w;              // wave handles nodes 4q..4q+3
    int n0 = quad * 4;                          // N % 16 == 0
    int c = lane & 15, j = lane >> 4;
    int sl = lane & 15, g = lane >> 4;

    int4 d4 = ((const int4*)deg)[quad];
    int dgA = min(d4.x, CAP), dgB = min(d4.y, CAP);
    int dgC = min(d4.z, CAP), dgD = min(d4.w, CAP);

    // coalesced: lane g*16+sl loads slot sl of node n0+g
    ushort_t idu = lst[(n0 + g) * CAP + sl];
    int dsel = (g == 0) ? dgA : (g == 1) ? dgB : (g == 2) ? dgC : dgD;
    int e_sel = (sl < dsel) ? (int)idu : E;

    __half2 hphA = Hp[(size_t)(n0 + 0) * 64 + lane];
    __half2 hphB = Hp[(size_t)(n0 + 1) * 64 + lane];
    __half2 hphC = Hp[(size_t)(n0 + 2) * 64 + lane];
    __half2 hphD = Hp[(size_t)(n0 + 3) * 64 + lane];
    h2v hpA, hpB, hpC, hpD;
    __builtin_memcpy(&hpA, &hphA, 4);
    __builtin_memcpy(&hpB, &hphB, 4);
    __builtin_memcpy(&hpC, &hphC, 4);
    __builtin_memcpy(&hpD, &hphD, 4);
    const h2v zv = (h2v)(_Float16)0.0f;

    int dmAB = max(dgA, dgB);
    int dmCD = max(dgC, dgD);
    int dmax = max(dmAB, dmCD);

    float aA0 = 0.0f, aA1 = 0.0f, aB0 = 0.0f, aB1 = 0.0f;
    float aC0 = 0.0f, aC1 = 0.0f, aD0 = 0.0f, aD1 = 0.0f;

    // ---- unconditional prefetch: slots 0..11 x 4 nodes (48 gathers) ----
    h2v sA[12], sB[12], sC[12], sD[12];
#pragma unroll
    for (int t = 0; t < 12; t++) {
        int eA = __builtin_amdgcn_readlane(e_sel, t);
        int eB = __builtin_amdgcn_readlane(e_sel, 16 + t);
        int eC = __builtin_amdgcn_readlane(e_sel, 32 + t);
        int eD = __builtin_amdgcn_readlane(e_sel, 48 + t);
        __half2 hv;
        hv = S[(size_t)eA * 64 + lane]; __builtin_memcpy(&sA[t], &hv, 4);
        hv = S[(size_t)eB * 64 + lane]; __builtin_memcpy(&sB[t], &hv, 4);
        hv = S[(size_t)eC * 64 + lane]; __builtin_memcpy(&sC[t], &hv, 4);
        hv = S[(size_t)eD * 64 + lane]; __builtin_memcpy(&sD[t], &hv, 4);
    }

    // ---- compute slots 0..7 (covers deg <= 8): two 4-slot fp16 groups ----
    {
        h2v pA, pB, pC, pD;
        SQ4(pA, sA, 0, hpA);  SQ4(pB, sB, 0, hpB);
        SQ4(pC, sC, 0, hpC);  SQ4(pD, sD, 0, hpD);
        h2v qA, qB, qC, qD;
        SQ4(qA, sA, 4, hpA);  SQ4(qB, sB, 4, hpB);
        SQ4(qC, sC, 4, hpC);  SQ4(qD, sD, 4, hpD);
        aA0 += (float)pA[0] + (float)qA[0];  aA1 += (float)pA[1] + (float)qA[1];
        aB0 += (float)pB[0] + (float)qB[0];  aB1 += (float)pB[1] + (float)qB[1];
        aC0 += (float)pC[0] + (float)qC[0];  aC1 += (float)pC[1] + (float)qC[1];
        aD0 += (float)pD[0] + (float)qD[0];  aD1 += (float)pD[1] + (float)qD[1];
    }

    // ---- pair AB: slots 8..11 (P~0.70), 12..15 (P~0.12) ----
    if (dmAB > 8) {
        h2v pA, pB;
        SQ4(pA, sA, 8, hpA);  SQ4(pB, sB, 8, hpB);
        aA0 += (float)pA[0];  aA1 += (float)pA[1];
        aB0 += (float)pB[0];  aB1 += (float)pB[1];
        if (dmAB > 12) {
            h2v uA[4], uB[4];
#pragma unroll
            for (int t = 0; t < 4; t++) {
                int eA = __builtin_amdgcn_readlane(e_sel, 12 + t);
                int eB = __builtin_amdgcn_readlane(e_sel, 28 + t);
                __half2 hv;
                hv = S[(size_t)eA * 64 + lane]; __builtin_memcpy(&uA[t], &hv, 4);
                hv = S[(size_t)eB * 64 + lane]; __builtin_memcpy(&uB[t], &hv, 4);
            }
            h2v vA, vB;
            SQ4(vA, uA, 0, hpA);  SQ4(vB, uB, 0, hpB);
            aA0 += (float)vA[0];  aA1 += (float)vA[1];
            aB0 += (float)vB[0];  aB1 += (float)vB[1];
        }
    }

    // ---- pair CD: slots 8..11, 12..15 ----
    if (dmCD > 8) {
        h2v pC, pD;
        SQ4(pC, sC, 8, hpC);  SQ4(pD, sD, 8, hpD);
        aC0 += (float)pC[0];  aC1 += (float)pC[1];
        aD0 += (float)pD[0];  aD1 += (float)pD[1];
        if (dmCD > 12) {
            h2v uC[4], uD[4];
#pragma unroll
            for (int t = 0; t < 4; t++) {
                int eC = __builtin_amdgcn_readlane(e_sel, 44 + t);
                int eD = __builtin_amdgcn_readlane(e_sel, 60 + t);
                __half2 hv;
                hv = S[(size_t)eC * 64 + lane]; __builtin_memcpy(&uC[t], &hv, 4);
                hv = S[(size_t)eD * 64 + lane]; __builtin_memcpy(&uD[t], &hv, 4);
            }
            h2v vC, vD;
            SQ4(vC, uC, 0, hpC);  SQ4(vD, uD, 0, hpD);
            aC0 += (float)vC[0];  aC1 += (float)vC[1];
            aD0 += (float)vD[0];  aD1 += (float)vD[1];
        }
    }

    // rare tails deg > 16 (P ~ 0.4%/node) — f32 path, cold
    if (dmax > 16) {
        float hA0 = (float)hpA[0], hA1 = (float)hpA[1];
        float hB0 = (float)hpB[0], hB1 = (float)hpB[1];
        float hC0 = (float)hpC[0], hC1 = (float)hpC[1];
        float hD0 = (float)hpD[0], hD1 = (float)hpD[1];
        for (int t = 16; t < dgA; t++) {
            int e = lst[(n0 + 0) * CAP + t];
            __half2 sh = S[(size_t)e * 64 + lane];
            aA0 += __builtin_amdgcn_sqrtf(fmaxf(__low2float(sh)  - hA0, 0.0f));
            aA1 += __builtin_amdgcn_sqrtf(fmaxf(__high2float(sh) - hA1, 0.0f));
        }
        for (int t = 16; t < dgB; t++) {
            int e = lst[(n0 + 1) * CAP + t];
            __half2 sh = S[(size_t)e * 64 + lane];
            aB0 += __builtin_amdgcn_sqrtf(fmaxf(__low2float(sh)  - hB0, 0.0f));
            aB1 += __builtin_amdgcn_sqrtf(fmaxf(__high2float(sh) - hB1, 0.0f));
        }
        for (int t = 16; t < dgC; t++) {
            int e = lst[(n0 + 2) * CAP + t];
            __half2 sh = S[(size_t)e * 64 + lane];
            aC0 += __builtin_amdgcn_sqrtf(fmaxf(__low2float(sh)  - hC0, 0.0f));
            aC1 += __builtin_amdgcn_sqrtf(fmaxf(__high2float(sh) - hC1, 0.0f));
        }
        for (int t = 16; t < dgD; t++) {
            int e = lst[(n0 + 3) * CAP + t];
            __half2 sh = S[(size_t)e * 64 + lane];
            aD0 += __builtin_amdgcn_sqrtf(fmaxf(__low2float(sh)  - hD0, 0.0f));
            aD1 += __builtin_amdgcn_sqrtf(fmaxf(__high2float(sh) - hD1, 0.0f));
        }
    }

    float nsA0 = __builtin_amdgcn_sqrtf((float)hpA[0]) + aA0 * SQRT_INV31;
    float nsA1 = __builtin_amdgcn_sqrtf((float)hpA[1]) + aA1 * SQRT_INV31;
    float nsB0 = __builtin_amdgcn_sqrtf((float)hpB[0]) + aB0 * SQRT_INV31;
    float nsB1 = __builtin_amdgcn_sqrtf((float)hpB[1]) + aB1 * SQRT_INV31;
    float nsC0 = __builtin_amdgcn_sqrtf((float)hpC[0]) + aC0 * SQRT_INV31;
    float nsC1 = __builtin_amdgcn_sqrtf((float)hpC[1]) + aC1 * SQRT_INV31;
    float nsD0 = __builtin_amdgcn_sqrtf((float)hpD[0]) + aD0 * SQRT_INV31;
    float nsD1 = __builtin_amdgcn_sqrtf((float)hpD[1]) + aD1 * SQRT_INV31;

    __shared__ float AHs[4][4][D1];             // wave-private [w][node][col]
    AHs[w][0][2 * lane] = nsA0;  AHs[w][0][2 * lane + 1] = nsA1;
    AHs[w][1][2 * lane] = nsB0;  AHs[w][1][2 * lane + 1] = nsB1;
    AHs[w][2][2 * lane] = nsC0;  AHs[w][2][2 * lane + 1] = nsC1;
    AHs[w][3][2 * lane] = nsD0;  AHs[w][3][2 * lane + 1] = nsD1;

    float vA = nsA0 + nsA1, vB = nsB0 + nsB1;
    float vC = nsC0 + nsC1, vD = nsD0 + nsD1;
#pragma unroll
    for (int m = 1; m < 64; m <<= 1) {
        vA += __shfl_xor(vA, m, 64);
        vB += __shfl_xor(vB, m, 64);
        vC += __shfl_xor(vC, m, 64);
        vD += __shfl_xor(vD, m, 64);
    }
    float rA = __builtin_amdgcn_rcpf(vA);
    float rB = __builtin_amdgcn_rcpf(vB);
    float rC = __builtin_amdgcn_rcpf(vC);
    float rD = __builtin_amdgcn_rcpf(vD);

    __threadfence_block();                      // LDS visibility within wave

    // ns[128] @ W1[128,16] for 4 nodes, sharing the W1t fragment.
    const float4* aAp = (const float4*)(&AHs[w][0][j * 32]);
    const float4* aBp = (const float4*)(&AHs[w][1][j * 32]);
    const float4* aCp = (const float4*)(&AHs[w][2][j * 32]);
    const float4* aDp = (const float4*)(&AHs[w][3][j * 32]);
    const float4* w1p = (const float4*)(W1t + c * D1 + j * 32);
    float pA = 0.0f, pB = 0.0f, pC = 0.0f, pD = 0.0f;
#pragma unroll
    for (int tt = 0; tt < 8; tt++) {
        float4 wv = w1p[tt];
        float4 xA = aAp[tt];
        float4 xB = aBp[tt];
        float4 xC = aCp[tt];
        float4 xD = aDp[tt];
        pA += xA.x * wv.x + xA.y * wv.y + xA.z * wv.z + xA.w * wv.w;
        pB += xB.x * wv.x + xB.y * wv.y + xB.z * wv.z + xB.w * wv.w;
        pC += xC.x * wv.x + xC.y * wv.y + xC.z * wv.z + xC.w * wv.w;
        pD += xD.x * wv.x + xD.y * wv.y + xD.z * wv.z + xD.w * wv.w;
    }
    pA += __shfl_xor(pA, 16, 64);  pA += __shfl_xor(pA, 32, 64);
    pB += __shfl_xor(pB, 16, 64);  pB += __shfl_xor(pB, 32, 64);
    pC += __shfl_xor(pC, 16, 64);  pC += __shfl_xor(pC, 32, 64);
    pD += __shfl_xor(pD, 16, 64);  pD += __shfl_xor(pD, 32, 64);

    float bb = b1[c];
    float oA = fminf(fmaxf(bb + pA * rA, CLAMP_LO), CLAMP_HI);
    float oB = fminf(fmaxf(bb + pB * rB, CLAMP_LO), CLAMP_HI);
    float oC = fminf(fmaxf(bb + pC * rC, CLAMP_LO), CLAMP_HI);
    float oD = fminf(fmaxf(bb + pD * rD, CLAMP_LO), CLAMP_HI);
    float qA = oA * oA, qB = oB * oB, qC = oC * oC, qD = oD * oD;
    // lane g*16+c stores node n0+g, col c  ->  Hp2 + 64*quad + lane (coalesced)
    float val = (g == 0) ? qA : (g == 1) ? qB : (g == 2) ? qC : qD;
    Hp2[(size_t)quad * 64 + lane] = val;
}

// S2[e,:] = sum over 32 nodes of Hp2[node,:] (d=16, fp32).
__global__ __launch_bounds__(256) void k_edge_sum2(const float* __restrict__ Hp2,
                                                   const int* __restrict__ idx,
                                                   float* __restrict__ S2, int E) {
    int e = blockIdx.x * 16 + (threadIdx.x >> 4);
    int col = threadIdx.x & 15;
    if (e >= E) return;
    float acc = 0.0f;
#pragma unroll
    for (int j = 0; j < K_EDGE; j++) {
        int n = idx[e * K_EDGE + j];
        acc += Hp2[(size_t)n * D2 + col];
    }
    S2[(size_t)e * D2 + col] = acc;
}

// Fused layer-2 node kernel, quad structure: FOUR nodes per wave,
// lane -> (g=lane>>4 node, col=lane&15). 12 unconditional S2 gathers
// (zero-row padding; S2 L2-resident); compute gated 8+4+4 on quad max.
__global__ __launch_bounds__(256) void k_node2(const float* __restrict__ Hp2,
                                               const float* __restrict__ S2,
                                               const int* __restrict__ deg,
                                               const ushort_t* __restrict__ lst,
                                               const float* __restrict__ W2,
                                               const float* __restrict__ b2,
                                               float* __restrict__ out, int N, int E) {
    int w = threadIdx.x >> 6;
    int lane = threadIdx.x & 63;
    int quad = blockIdx.x * 4 + w;              // wave handles nodes 4q..4q+3
    int n0 = quad * 4;                          // N % 16 == 0
    int col = lane & 15;
    int g = lane >> 4;
    int nn = n0 + g;

    int4 d4 = ((const int4*)deg)[quad];
    int dgA = min(d4.x, CAP), dgB = min(d4.y, CAP);
    int dgC = min(d4.z, CAP), dgD = min(d4.w, CAP);
    int dsel = (g == 0) ? dgA : (g == 1) ? dgB : (g == 2) ? dgC : dgD;

    ushort_t idu = lst[(size_t)nn * CAP + col];        // slot col of node g
    int e_sel = (col < dsel) ? (int)idu : E;           // E = zero row of S2

    float hp = Hp2[(size_t)n0 * D2 + lane];            // coalesced 256B/wave
    int dmax = max(max(dgA, dgB), max(dgC, dgD));

    // unconditional: slots 0..11 of own node
    int ev[12];
#pragma unroll
    for (int t = 0; t < 12; t++) ev[t] = __shfl(e_sel, g * 16 + t, 64);
    float sv[12];
#pragma unroll
    for (int t = 0; t < 12; t++) sv[t] = S2[(size_t)ev[t] * D2 + col];

    float acc = 0.0f;
#pragma unroll
    for (int t = 0; t < 8; t++)
        acc += __builtin_amdgcn_sqrtf(fmaxf(sv[t] - hp, 0.0f));
    if (dmax > 8) {
#pragma unroll
        for (int t = 8; t < 12; t++)
            acc += __builtin_amdgcn_sqrtf(fmaxf(sv[t] - hp, 0.0f));
        if (dmax > 12) {
#pragma unroll
            for (int t = 12; t < 16; t++) {
                int e = __shfl(e_sel, g * 16 + t, 64);
                float s = S2[(size_t)e * D2 + col];
                acc += __builtin_amdgcn_sqrtf(fmaxf(s - hp, 0.0f));
            }
        }
    }
    if (dmax > 16) {                            // rare tails (P ~ 0.4%/node)
        for (int t = 16; t < dsel; t++) {
            int e = lst[(size_t)nn * CAP + t];  // broadcast within group
            float s = S2[(size_t)e * D2 + col];
            acc += __builtin_amdgcn_sqrtf(fmaxf(s - hp, 0.0f));
        }
    }
    float ns = __builtin_amdgcn_sqrtf(hp) + acc * SQRT_INV31;

    // rowsum over the 16 cols within each 16-lane group
    float v = ns;
#pragma unroll
    for (int m = 1; m < 16; m <<= 1) v += __shfl_xor(v, m, 64);
    float r = __builtin_amdgcn_rcpf(v);

    __shared__ float AHs[4][4][D2];             // wave-private [w][node][col]
    AHs[w][g][col] = ns * r;
    __threadfence_block();

    if (lane < C_OUT) {
        float o0 = b2[lane], o1 = o0, o2 = o0, o3 = o0;
#pragma unroll
        for (int i = 0; i < D2; i++) {
            float wv = W2[i * C_OUT + lane];
            o0 += AHs[w][0][i] * wv;
            o1 += AHs[w][1][i] * wv;
            o2 += AHs[w][2][i] * wv;
            o3 += AHs[w][3][i] * wv;
        }
        out[(size_t)(n0 + 0) * C_OUT + lane] = o0;
        out[(size_t)(n0 + 1) * C_OUT + lane] = o1;
        out[(size_t)(n0 + 2) * C_OUT + lane] = o2;
        out[(size_t)(n0 + 3) * C_OUT + lane] = o3;
    }
}

extern "C" void kernel_launch(void* const* d_in, const int* in_sizes, int n_in,
                              void* d_out, int out_size, void* d_ws, size_t ws_size,
                              hipStream_t stream) {
    const float* x   = (const float*)d_in[0];
    const int*   idx = (const int*)d_in[1];
    const float* W1  = (const float*)d_in[2];
    const float* b1  = (const float*)d_in[3];
    const float* W2  = (const float*)d_in[4];
    const float* b2  = (const float*)d_in[5];
    float* out = (float*)d_out;

    int N = in_sizes[0] / D1;     // 100000
    int E = in_sizes[1] / K_EDGE; // 25000

    // workspace layout (S and S2 have one extra zero row at index E)
    __half2* Hp = (__half2*)d_ws;                          // N*64 half2
    __half2* S  = Hp + (size_t)N * 64;                     // (E+1)*64 half2
    float* Hp2  = (float*)(S + (size_t)(E + 1) * 64);      // N*16 fp32
    float* S2   = Hp2 + (size_t)N * D2;                    // (E+1)*16 fp32
    float* W1t  = S2 + (size_t)(E + 1) * D2;               // 16*128 fp32
    int*   deg  = (int*)(W1t + D1 * D2);                   // N ints
    ushort_t* lst = (ushort_t*)(deg + N);                  // N*CAP uint16

    int n4 = N * D1 / 4;           // 3200000

    k_setup<<<(n4 + 255) / 256, 256, 0, stream>>>(x, Hp, W1, W1t, S, S2, deg,
                                                  (uint2*)lst, n4, N, E);
    int g4 = (E + 15) / 16;        // blocks per quarter
    k_edge_sum<<<4 * g4, 256, 0, stream>>>(Hp, idx, S, deg,
                                           (unsigned int*)lst, E);
    k_node1<<<N / 16, 256, 0, stream>>>(Hp, S, deg, lst, W1t, b1, Hp2, N, E);
    k_edge_sum2<<<(E + 15) / 16, 256, 0, stream>>>(Hp2, idx, S2, E);
    k_node2<<<N / 16, 256, 0, stream>>>(Hp2, S2, deg, lst, W2, b2, out, N, E);
}